// Round 1
// baseline (873.107 us; speedup 1.0000x reference)
//
#include <hip/hip_runtime.h>
#include <math.h>

#define SS 1024           // sequence length
#define DD 1024           // feature dim
#define NB 64             // batch
#define NT 34             // number of states (33 tags + BOS)
#define MID 511           // forward computes alpha_MID; backward computes beta_MID

// workspace layout (floats)
#define WS_BOS   0                    // [64*1024] proj[:,:,33]
#define WS_ALPHA (NB*SS)              // [64*34]
#define WS_BETA  (WS_ALPHA + NB*NT)   // [64*34]
#define WS_SCORE (WS_BETA + NB*NT)    // [64]

__device__ __forceinline__ float warp_sum64(float x) {
  #pragma unroll
  for (int off = 32; off > 0; off >>= 1) x += __shfl_down(x, off, 64);
  return x;
}

// read projected emission (b,t,j): j<33 from logits (d_out+1), j==33 from bos col
__device__ __forceinline__ float read_em(const float* __restrict__ logits,
                                         const float* __restrict__ bos,
                                         int b, int t, int j) {
  if (j < 33) return logits[(size_t)(b * SS + t) * 33 + j];
  if (j == 33) return bos[b * SS + t];
  return 0.0f;
}

// ---------------- GEMM: proj = em @ W + b ----------------
// grid 1024 x block 64; one row (b,t) per lane; W operands wave-uniform (SGPR).
__global__ void gemm_proj(const float* __restrict__ em, const float* __restrict__ W,
                          const float* __restrict__ bias,
                          float* __restrict__ out_logits, float* __restrict__ bos) {
  int row = blockIdx.x * 64 + threadIdx.x;
  const float4* ar = (const float4*)(em + (size_t)row * DD);
  float acc[NT];
  #pragma unroll
  for (int j = 0; j < NT; ++j) acc[j] = bias[j];

  float4 a = ar[0];
  for (int kt = 0; kt < DD / 4; ++kt) {
    float4 acur = a;
    int nxt = kt + 1 < DD / 4 ? kt + 1 : DD / 4 - 1;
    a = ar[nxt];                                   // prefetch next 16B
    #pragma unroll
    for (int u = 0; u < 4; ++u) {
      int kk = kt * 4 + u;
      float av = (u == 0) ? acur.x : (u == 1) ? acur.y : (u == 2) ? acur.z : acur.w;
      #pragma unroll
      for (int j = 0; j < NT; ++j)
        acc[j] = fmaf(av, W[kk * NT + j], acc[j]); // uniform -> s_load
    }
  }
  float* o = out_logits + (size_t)row * 33;
  #pragma unroll
  for (int j = 0; j < 33; ++j) o[j] = acc[j];
  bos[row] = acc[NT - 1];
}

// ---------------- chains (fwd/bwd) + supervised score ----------------
// blocks 0..63: forward batch b   (alpha_0 .. alpha_MID)   [wave0 only]
// blocks 64..127: backward batch  (beta_{S-1}=0 .. beta_MID)[wave0 only]
// blocks 128..191: score batch    (256 threads)
__global__ __launch_bounds__(256) void chains_score(
    const float* __restrict__ logits, const float* __restrict__ bosc,
    const float* __restrict__ T, const float* __restrict__ mask,
    const int* __restrict__ tags, float* __restrict__ alpha_o,
    float* __restrict__ beta_o, float* __restrict__ score_o) {
  int blk = blockIdx.x;
  if (blk < 128) {
    if (threadIdx.x >= 64) return;   // single-wave chain, no barriers below
    const int lane = threadIdx.x;
    const int b = blk & 63;
    const bool fwd = blk < 64;
    const int jc = lane < NT ? lane : NT - 1;   // clamp to avoid OOB T reads
    float eT[NT];

    if (fwd) {
      #pragma unroll
      for (int i = 0; i < NT; ++i) {            // column jc of exp(T)
        float v = __expf(T[i * NT + jc]);
        eT[i] = (lane < NT) ? v : 0.0f;
      }
      float alpha = -INFINITY;
      if (lane < NT) alpha = T[(NT - 1) * NT + lane] + read_em(logits, bosc, b, 0, lane);
      float eA = (lane < NT) ? read_em(logits, bosc, b, 1, lane) : 0.0f;
      float eB = (lane < NT) ? read_em(logits, bosc, b, 2, lane) : 0.0f;
      float mA = mask[b * SS + 1], mB = mask[b * SS + 2];
      for (int t = 1; t <= MID; ++t) {
        float e = eA, m = mA;
        eA = eB; mA = mB;
        eB = (lane < NT) ? read_em(logits, bosc, b, t + 2, lane) : 0.0f; // t+2<=513 in-bounds
        mB = mask[b * SS + t + 2];
        if (m > 0.5f) {
          float M = __shfl(alpha, 0, 64);       // shared shift (lane0 finite)
          float ea = __expf(alpha - M);         // -inf -> 0, lanes>=34 stay 0
          float s0 = 0.f, s1 = 0.f, s2 = 0.f, s3 = 0.f;
          #pragma unroll
          for (int i = 0; i < 32; i += 4) {
            s0 = fmaf(__shfl(ea, i + 0, 64), eT[i + 0], s0);
            s1 = fmaf(__shfl(ea, i + 1, 64), eT[i + 1], s1);
            s2 = fmaf(__shfl(ea, i + 2, 64), eT[i + 2], s2);
            s3 = fmaf(__shfl(ea, i + 3, 64), eT[i + 3], s3);
          }
          s0 = fmaf(__shfl(ea, 32, 64), eT[32], s0);
          s1 = fmaf(__shfl(ea, 33, 64), eT[33], s1);
          float s = (s0 + s1) + (s2 + s3);
          alpha = M + __logf(s) + e;            // j==33: s==0 -> -inf (correct)
        }
      }
      if (lane < NT) alpha_o[b * NT + lane] = alpha;
    } else {
      #pragma unroll
      for (int i = 0; i < NT; ++i) {            // row jc of exp(T)
        float v = __expf(T[jc * NT + i]);
        eT[i] = (lane < NT) ? v : 0.0f;
      }
      float beta = 0.0f;
      float eA = (lane < NT) ? read_em(logits, bosc, b, SS - 1, lane) : 0.0f;
      float eB = (lane < NT) ? read_em(logits, bosc, b, SS - 2, lane) : 0.0f;
      float mA = mask[b * SS + SS - 1], mB = mask[b * SS + SS - 2];
      for (int t = SS - 1; t > MID; --t) {
        float e = eA, m = mA;
        eA = eB; mA = mB;
        int tp = t - 2 >= 0 ? t - 2 : 0;
        eB = (lane < NT) ? read_em(logits, bosc, b, tp, lane) : 0.0f;
        mB = mask[b * SS + tp];
        if (m > 0.5f) {
          float g = beta + e;                   // g_j = em_t[j] + beta_t[j]
          float M = __shfl(g, 0, 64);
          float eg = __expf(g - M);
          float s0 = 0.f, s1 = 0.f, s2 = 0.f, s3 = 0.f;
          #pragma unroll
          for (int i = 0; i < 32; i += 4) {
            s0 = fmaf(__shfl(eg, i + 0, 64), eT[i + 0], s0);
            s1 = fmaf(__shfl(eg, i + 1, 64), eT[i + 1], s1);
            s2 = fmaf(__shfl(eg, i + 2, 64), eT[i + 2], s2);
            s3 = fmaf(__shfl(eg, i + 3, 64), eT[i + 3], s3);
          }
          s0 = fmaf(__shfl(eg, 32, 64), eT[32], s0);
          s1 = fmaf(__shfl(eg, 33, 64), eT[33], s1);
          float s = (s0 + s1) + (s2 + s3);
          beta = M + __logf(s);                 // lanes>=34 -> -inf, never read
        }
      }
      if (lane < NT) beta_o[b * NT + lane] = beta;
    }
  } else {
    // supervised path score
    int b = blk - 128;
    float local = 0.0f;
    for (int t = threadIdx.x; t < SS; t += 256) {
      if (t == 0) {
        int tg = tags[b * SS];
        local += T[(NT - 1) * NT + tg] + logits[(size_t)(b * SS) * 33 + tg];
      } else {
        int tg = tags[b * SS + t];
        int tp = tags[b * SS + t - 1];
        float m = mask[b * SS + t];
        local += m * (logits[(size_t)(b * SS + t) * 33 + tg] + T[tp * NT + tg]);
      }
    }
    __shared__ float red[4];
    float w = warp_sum64(local);
    if ((threadIdx.x & 63) == 0) red[threadIdx.x >> 6] = w;
    __syncthreads();
    if (threadIdx.x == 0) score_o[b] = red[0] + red[1] + red[2] + red[3];
  }
}

// ---------------- combine: loss = sum_b (Z_b - score_b) ----------------
__global__ void combine(const float* __restrict__ alpha, const float* __restrict__ beta,
                        const float* __restrict__ score, float* __restrict__ out) {
  int b = threadIdx.x;  // 64 threads
  float v[NT];
  float M = -INFINITY;
  #pragma unroll
  for (int i = 0; i < NT; ++i) {
    v[i] = alpha[b * NT + i] + beta[b * NT + i];
    M = fmaxf(M, v[i]);
  }
  float s = 0.0f;
  #pragma unroll
  for (int i = 0; i < NT; ++i) s += __expf(v[i] - M);
  float part = (M + __logf(s)) - score[b];
  float tot = warp_sum64(part);
  if (b == 0) out[0] = tot;
}

extern "C" void kernel_launch(void* const* d_in, const int* in_sizes, int n_in,
                              void* d_out, int out_size, void* d_ws, size_t ws_size,
                              hipStream_t stream) {
  const float* em   = (const float*)d_in[0];
  const int*   tags = (const int*)d_in[1];
  const float* mask = (const float*)d_in[2];
  const float* W    = (const float*)d_in[3];
  const float* bias = (const float*)d_in[4];
  const float* T    = (const float*)d_in[5];

  float* out = (float*)d_out;
  float* ws  = (float*)d_ws;
  float* bos   = ws + WS_BOS;
  float* alpha = ws + WS_ALPHA;
  float* beta  = ws + WS_BETA;
  float* score = ws + WS_SCORE;
  float* logits = out + 1;   // d_out = [loss, logits(B,S,33)]

  hipLaunchKernelGGL(gemm_proj, dim3(NB * SS / 64), dim3(64), 0, stream,
                     em, W, bias, logits, bos);
  hipLaunchKernelGGL(chains_score, dim3(192), dim3(256), 0, stream,
                     logits, bos, T, mask, tags, alpha, beta, score);
  hipLaunchKernelGGL(combine, dim3(1), dim3(64), 0, stream,
                     alpha, beta, score, out);
}